// Round 1
// baseline (492.879 us; speedup 1.0000x reference)
//
#include <hip/hip_runtime.h>

// PermutationalLayer: out[b, i] = z[b, perm_idx[i]]  (pure gather, fp32)
//
// Key structure from _make_perm: perm_idx[2k] = 2*perm[k] (even),
// perm_idx[2k+1] = 2*perm[k]+1. So output pair (2k, 2k+1) = input pair
// starting at even index perm_idx[2k]. We gather at float2 granularity and
// store at float4 granularity (two pairs per store, fully coalesced).
//
// One block per row (4096 floats = 2048 float2 = 1024 float4): the 16 KiB
// gather window stays L1/L2 resident, so each HBM line is fetched once even
// though the gather order is random within the row.

#define DATA_DIM 4096
#define PAIRS    (DATA_DIM / 2)   // 2048 float2 per row
#define QUADS    (DATA_DIM / 4)   // 1024 float4 per row
#define BLOCK    256

__global__ __launch_bounds__(BLOCK) void perm_gather_kernel(
    const float2* __restrict__ z2,      // [batch, PAIRS]
    const int4*   __restrict__ pidx4,   // [QUADS] : perm_idx viewed as int4
    float4*       __restrict__ out4)    // [batch, QUADS]
{
    const int row = blockIdx.x;
    const float2* __restrict__ zrow = z2 + (size_t)row * PAIRS;
    float4* __restrict__ orow       = out4 + (size_t)row * QUADS;

    const int t = threadIdx.x;
#pragma unroll
    for (int q = t; q < QUADS; q += BLOCK) {   // 4 iterations
        const int4 p = pidx4[q];
        // p.x = 2*perm[2q]   (even), p.y = p.x+1
        // p.z = 2*perm[2q+1] (even), p.w = p.z+1
        const float2 a = zrow[p.x >> 1];
        const float2 b = zrow[p.z >> 1];
        orow[q] = make_float4(a.x, a.y, b.x, b.y);
    }
}

extern "C" void kernel_launch(void* const* d_in, const int* in_sizes, int n_in,
                              void* d_out, int out_size, void* d_ws, size_t ws_size,
                              hipStream_t stream) {
    const float2* z2    = (const float2*)d_in[0];
    const int4*   pidx4 = (const int4*)d_in[1];
    float4*       out4  = (float4*)d_out;

    const int batch = in_sizes[0] / DATA_DIM;   // 16384

    perm_gather_kernel<<<batch, BLOCK, 0, stream>>>(z2, pidx4, out4);
}

// Round 2
// 431.267 us; speedup vs baseline: 1.1429x; 1.1429x over previous
//
#include <hip/hip_runtime.h>

// PermutationalLayer: out[b, i] = z[b, perm_idx[i]]  (pure gather, fp32)
//
// R0 lesson: direct global gather runs at 3.6 cyc/lane-address (divergent
// VMEM), 195 us @ 26% HBM. Fix: stage the row in LDS (coalesced float4 VMEM),
// do the random gather in LDS where divergence is cheap, store coalesced.
//
// Structure from _make_perm: perm_idx[2k] = 2*perm[k], perm_idx[2k+1] =
// perm_idx[2k]+1 -> gather granularity is float2, store granularity float4.

#define DATA_DIM 4096
#define PAIRS    (DATA_DIM / 2)   // 2048 float2 per row
#define QUADS    (DATA_DIM / 4)   // 1024 float4 per row
#define BLOCK    256
#define ROWS     2                // rows per block; 2 * 16 KiB = 32 KiB LDS

__global__ __launch_bounds__(BLOCK) void perm_gather_lds_kernel(
    const float4* __restrict__ z4,      // [batch, QUADS]
    const int4*   __restrict__ pidx4,   // [QUADS]
    float4*       __restrict__ out4)    // [batch, QUADS]
{
    __shared__ float2 srow[ROWS][PAIRS];          // 32 KiB

    const int row0 = blockIdx.x * ROWS;
    const int t    = threadIdx.x;

    // ---- stage ROWS rows into LDS, fully coalesced float4 loads ----
#pragma unroll
    for (int r = 0; r < ROWS; ++r) {
        const float4* __restrict__ zrow = z4 + (size_t)(row0 + r) * QUADS;
        float4* s4 = (float4*)srow[r];
#pragma unroll
        for (int q = t; q < QUADS; q += BLOCK)    // 4 iters
            s4[q] = zrow[q];
    }
    __syncthreads();

    // ---- gather from LDS (divergence lands on LDS banks, not VMEM),
    //      store fully coalesced float4 ----
#pragma unroll
    for (int q = t; q < QUADS; q += BLOCK) {      // 4 iters
        const int4 p  = pidx4[q];                 // L1-resident after 1st block/CU
        const int  ia = p.x >> 1;                 // even pair start
        const int  ib = p.z >> 1;
#pragma unroll
        for (int r = 0; r < ROWS; ++r) {
            const float2 a = srow[r][ia];
            const float2 b = srow[r][ib];
            out4[(size_t)(row0 + r) * QUADS + q] = make_float4(a.x, a.y, b.x, b.y);
        }
    }
}

extern "C" void kernel_launch(void* const* d_in, const int* in_sizes, int n_in,
                              void* d_out, int out_size, void* d_ws, size_t ws_size,
                              hipStream_t stream) {
    const float4* z4    = (const float4*)d_in[0];
    const int4*   pidx4 = (const int4*)d_in[1];
    float4*       out4  = (float4*)d_out;

    const int batch = in_sizes[0] / DATA_DIM;     // 16384
    perm_gather_lds_kernel<<<batch / ROWS, BLOCK, 0, stream>>>(z4, pidx4, out4);
}

// Round 3
// 421.325 us; speedup vs baseline: 1.1698x; 1.0236x over previous
//
#include <hip/hip_runtime.h>

// PermutationalLayer: out[b, i] = z[b, perm_idx[i]]  (pure gather, fp32)
//
// R0: direct global gather = VMEM-divergence-bound, 195 us @ 26% HBM.
// R1: LDS-staged gather, ~133 us. Limits: 20 waves/CU (32 KiB LDS) and
//     global->VGPR->ds_write staging round trip.
// R2: ROWS=1 (16 KiB LDS -> 8 blocks/CU = 32 waves/CU, occupancy cap) +
//     global_load_lds width-16 DMA staging (no VGPR round trip) + perm
//     indices prefetched to registers before the barrier.
//
// Structure from _make_perm: perm_idx[2k] = 2*perm[k], perm_idx[2k+1] =
// perm_idx[2k]+1 -> gather granularity float2, store granularity float4.

#define DATA_DIM 4096
#define PAIRS    (DATA_DIM / 2)   // 2048 float2 per row
#define QUADS    (DATA_DIM / 4)   // 1024 float4 per row
#define BLOCK    256
#define PER_T    (QUADS / BLOCK)  // 4

__global__ __launch_bounds__(BLOCK) void perm_gather_lds_kernel(
    const float4* __restrict__ z4,      // [batch, QUADS]
    const int4*   __restrict__ pidx4,   // [QUADS]
    float4*       __restrict__ out4)    // [batch, QUADS]
{
    __shared__ float4 s4[QUADS];        // 16 KiB: one row

    const int row = blockIdx.x;
    const int t   = threadIdx.x;
    const float4* __restrict__ zrow = z4 + (size_t)row * QUADS;

    // Prefetch perm indices into registers (independent of the staging DMA;
    // L1-resident after the first block on each CU).
    int4 p[PER_T];
#pragma unroll
    for (int k = 0; k < PER_T; ++k)
        p[k] = pidx4[t + k * BLOCK];

    // Async global->LDS DMA, 16 B/lane, contiguous (wave-uniform base +
    // lane*16 — the exact layout global_load_lds requires).
#pragma unroll
    for (int k = 0; k < PER_T; ++k) {
        __builtin_amdgcn_global_load_lds(
            (const __attribute__((address_space(1))) void*)(zrow + t + k * BLOCK),
            (__attribute__((address_space(3))) void*)(s4 + t + k * BLOCK),
            16, 0, 0);
    }
    __syncthreads();   // drains the DMA (vmcnt) + barrier

    // Random gather from LDS (divergence on LDS banks, ~free), coalesced
    // float4 stores.
    const float2* s2 = (const float2*)s4;
    float4* __restrict__ orow = out4 + (size_t)row * QUADS;
#pragma unroll
    for (int k = 0; k < PER_T; ++k) {
        const float2 a = s2[p[k].x >> 1];
        const float2 b = s2[p[k].z >> 1];
        orow[t + k * BLOCK] = make_float4(a.x, a.y, b.x, b.y);
    }
}

extern "C" void kernel_launch(void* const* d_in, const int* in_sizes, int n_in,
                              void* d_out, int out_size, void* d_ws, size_t ws_size,
                              hipStream_t stream) {
    const float4* z4    = (const float4*)d_in[0];
    const int4*   pidx4 = (const int4*)d_in[1];
    float4*       out4  = (float4*)d_out;

    const int batch = in_sizes[0] / DATA_DIM;   // 16384
    perm_gather_lds_kernel<<<batch, BLOCK, 0, stream>>>(z4, pidx4, out4);
}